// Round 4
// baseline (134.704 us; speedup 1.0000x reference)
//
#include <hip/hip_runtime.h>
#include <stdint.h>

#define NBL 8
#define MBS 512   // rows per blade
#define CIN 1024  // K per blade block
#define UQ  1024  // output cols per blade

// sigma[i][k]: j such that blade_i * blade_j = sign * blade_k ; sg[i][k] = sign
__device__ __constant__ int c_sigma[8][8] = {
  {0,1,2,3,4,5,6,7},
  {1,0,4,5,2,3,7,6},
  {2,4,0,6,1,7,3,5},
  {3,5,6,0,7,1,2,4},
  {4,2,1,7,0,6,5,3},
  {5,3,7,1,6,0,4,2},
  {6,7,3,2,5,4,0,1},
  {7,6,5,4,3,2,1,0},
};
__device__ __constant__ int c_sg[8][8] = {
  { 1, 1, 1, 1, 1, 1, 1, 1},
  { 1, 1, 1, 1, 1, 1, 1, 1},
  { 1,-1, 1, 1,-1,-1, 1,-1},
  { 1,-1,-1, 1, 1,-1,-1, 1},
  {-1, 1,-1,-1, 1, 1,-1, 1},
  {-1, 1, 1,-1,-1, 1, 1,-1},
  {-1,-1, 1,-1, 1,-1, 1, 1},
  {-1,-1, 1,-1, 1,-1, 1, 1},
};

typedef short bf16x8 __attribute__((ext_vector_type(8)));
typedef float f32x4 __attribute__((ext_vector_type(4)));

__device__ __forceinline__ uint32_t f2bf(float f) {
  uint32_t u = __float_as_uint(f);
  return (u + 0x7fffu + ((u >> 16) & 1u)) >> 16;  // RNE
}
__device__ __forceinline__ uint32_t pk2(float lo, float hi) {
  return f2bf(lo) | (f2bf(hi) << 16);
}

// x (4096x1024 f32) -> X+ bf16 and X- bf16 (sign flip = xor 0x8000)
__global__ void cvt_x_kernel(const float4* __restrict__ x,
                             uint4* __restrict__ xp, uint4* __restrict__ xn) {
  int idx = blockIdx.x * blockDim.x + threadIdx.x;
  float4 a = x[2 * idx];
  float4 b = x[2 * idx + 1];
  uint4 p;
  p.x = pk2(a.x, a.y); p.y = pk2(a.z, a.w);
  p.z = pk2(b.x, b.y); p.w = pk2(b.z, b.w);
  uint4 n;
  n.x = p.x ^ 0x80008000u; n.y = p.y ^ 0x80008000u;
  n.z = p.z ^ 0x80008000u; n.w = p.w ^ 0x80008000u;
  xp[idx] = p;
  xn[idx] = n;
}

// W [1024][8192] f32 -> Wt [8192][1024] bf16
__global__ void cvt_w_kernel(const float* __restrict__ w, uint16_t* __restrict__ wt) {
  __shared__ float tile[32][33];
  int tx = threadIdx.x & 31, ty = threadIdx.x >> 5;  // 32x8
  int n0 = blockIdx.x * 32;
  int c0 = blockIdx.y * 32;
#pragma unroll
  for (int r = 0; r < 4; ++r) {
    int c = c0 + ty + r * 8;
    tile[ty + r * 8][tx] = w[(size_t)c * 8192 + n0 + tx];
  }
  __syncthreads();
#pragma unroll
  for (int r = 0; r < 4; ++r) {
    int n = n0 + ty + r * 8;
    wt[(size_t)n * 1024 + c0 + tx] = (uint16_t)f2bf(tile[tx][ty + r * 8]);
  }
}

// out[r][c] = bias[(r>>9)*1024 + c]  (prefill; GEMM atomically accumulates)
__global__ void bias_fill(const float* __restrict__ bias, float4* __restrict__ out) {
  int idx = blockIdx.x * 256 + threadIdx.x;
  int row = idx >> 8;
  int c4 = idx & 255;
  int k = row >> 9;
  out[idx] = ((const float4*)(bias + k * UQ))[c4];
}

// ---- 256x256x(BK=64) 8-phase GEMM, split-K=4, T2 swizzle, counted vmcnt ----
// Phase body: 12 ds_read_b128 + 2 global_load_lds staging + bar + 16 MFMA + bar.
// Staging ledger (units = 64 rows x 64 k; tile tau, dbuf tau&1):
//   p0: B0,B1(tau+1)  p1: B2,B3(tau+1) [vmcnt(6) at end]
//   p2: A1,A3(tau+1)  p3: A0,A2(tau+2) [vmcnt(4) at end]
// vmcnt(4) at each tile boundary proves all of next tile's p0-needed units
// landed (allowed outstanding = A0,A2(next)+A1,A3(cur) = 4 loads); vmcnt(6)
// at p1-end proves A1,A3(cur) landed before p2 reads them.
#define PHASE(MH, NH, STAGE, VMWAIT)                                          \
  {                                                                           \
    const uint16_t* la = dynlds + (size_t)(d * 2 + 0) * 16384;                \
    const uint16_t* lb = dynlds + (size_t)(d * 2 + 1) * 16384;                \
    bf16x8 af[4][2], bf[2][2];                                                \
    _Pragma("unroll")                                                         \
    for (int f = 0; f < 4; ++f) {                                             \
      const int R = wr * 128 + MH * 64 + f * 16 + r15;                        \
      _Pragma("unroll")                                                       \
      for (int kk = 0; kk < 2; ++kk) {                                        \
        const int gc = kk * 4 + hi;                                           \
        af[f][kk] = *(const bf16x8*)(la + R * 64 + ((gc ^ (R & 7)) << 3));    \
      }                                                                       \
    }                                                                         \
    _Pragma("unroll")                                                         \
    for (int gg = 0; gg < 2; ++gg) {                                          \
      const int C = wc * 64 + NH * 32 + gg * 16 + r15;                        \
      _Pragma("unroll")                                                       \
      for (int kk = 0; kk < 2; ++kk) {                                        \
        const int gc = kk * 4 + hi;                                           \
        bf[gg][kk] = *(const bf16x8*)(lb + C * 64 + ((gc ^ (C & 7)) << 3));   \
      }                                                                       \
    }                                                                         \
    STAGE;                                                                    \
    asm volatile("s_barrier" ::: "memory");                                   \
    __builtin_amdgcn_sched_barrier(0);                                        \
    __builtin_amdgcn_s_setprio(1);                                            \
    _Pragma("unroll")                                                         \
    for (int kk = 0; kk < 2; ++kk)                                            \
      _Pragma("unroll")                                                       \
      for (int f = 0; f < 4; ++f)                                             \
        _Pragma("unroll")                                                     \
        for (int gg = 0; gg < 2; ++gg)                                        \
          acc[MH * 4 + f][NH * 2 + gg] =                                      \
              __builtin_amdgcn_mfma_f32_16x16x32_bf16(                        \
                  af[f][kk], bf[gg][kk], acc[MH * 4 + f][NH * 2 + gg], 0, 0, 0); \
    __builtin_amdgcn_s_setprio(0);                                            \
    VMWAIT;                                                                   \
    asm volatile("s_barrier" ::: "memory");                                   \
    __builtin_amdgcn_sched_barrier(0);                                        \
  }

__global__ __launch_bounds__(512, 1) void ga_gemm8(
    const uint16_t* __restrict__ xp, const uint16_t* __restrict__ xn,
    const uint16_t* __restrict__ wt, float* __restrict__ out) {
  extern __shared__ uint16_t dynlds[];  // [2 dbuf][A,B][256][64] = 128 KiB

  const int tid = threadIdx.x;
  const int bid = blockIdx.x;
  const int s   = bid >> 6;          // K-split 0..3
  const int rem = bid & 63;
  const int k   = rem >> 3;          // blade 0..7
  const int mt  = (rem >> 2) & 1;    // m-tile 0..1
  const int ut  = rem & 3;           // n-tile 0..3
  const int lane = tid & 63;
  const int wid  = tid >> 6;         // 0..7
  const int wr   = wid >> 2;         // 0..1
  const int wc   = wid & 3;          // 0..3
  const int r15 = lane & 15, hi = lane >> 4;

  f32x4 acc[8][4];
  const f32x4 z = {0.f, 0.f, 0.f, 0.f};
#pragma unroll
  for (int a = 0; a < 8; ++a)
#pragma unroll
    for (int b = 0; b < 4; ++b) acc[a][b] = z;

  // stage one 64-row unit (1 load/thread). part: 0=A,1=B. u: 0..3. g: global K-tile.
  auto stage_unit = [&](int g, int d_, int part, int u) {
    const int i  = g >> 4;
    const int c0 = (g & 15) << 6;
    const int rl = tid >> 3;                      // 0..63
    const int cs = (tid & 7) ^ (rl & 7);          // T2 pre-swizzled source chunk
    const uint16_t* src;
    if (part == 0) {
      src = ((c_sg[i][k] > 0) ? xp : xn) +
            (size_t)(i * MBS + mt * 256 + u * 64 + rl) * CIN + c0 + cs * 8;
    } else {
      src = wt + (size_t)(c_sigma[i][k] * UQ + ut * 256 + u * 64 + rl) * CIN + c0 + cs * 8;
    }
    uint16_t* dst = dynlds + (size_t)(d_ * 2 + part) * 16384 + (u * 512 + tid) * 8;
    __builtin_amdgcn_global_load_lds(
        (const __attribute__((address_space(1))) uint32_t*)src,
        (__attribute__((address_space(3))) uint32_t*)dst, 16, 0, 0);
  };

  const int t0 = s * 32;  // 32 K-tiles of 64 per block

  // prologue: tile0 (8 units) + A0,A2(tile1); then wait all but newest 4
  stage_unit(t0, 0, 0, 0); stage_unit(t0, 0, 0, 2);
  stage_unit(t0, 0, 1, 0); stage_unit(t0, 0, 1, 1);
  stage_unit(t0, 0, 1, 2); stage_unit(t0, 0, 1, 3);
  stage_unit(t0, 0, 0, 1); stage_unit(t0, 0, 0, 3);
  stage_unit(t0 + 1, 1, 0, 0); stage_unit(t0 + 1, 1, 0, 2);
  asm volatile("s_waitcnt vmcnt(4)" ::: "memory");
  asm volatile("s_barrier" ::: "memory");
  __builtin_amdgcn_sched_barrier(0);

  for (int tau = 0; tau < 32; ++tau) {
    const int d  = tau & 1;
    const int d1 = d ^ 1;
    const int g1 = t0 + tau + 1;
    const bool st1 = (tau + 1) < 32;
    const bool st2 = (tau + 2) < 32;
    PHASE(0, 0, { if (st1) { stage_unit(g1, d1, 1, 0); stage_unit(g1, d1, 1, 1); } }, )
    PHASE(0, 1, { if (st1) { stage_unit(g1, d1, 1, 2); stage_unit(g1, d1, 1, 3); } },
          asm volatile("s_waitcnt vmcnt(6)" ::: "memory");)
    PHASE(1, 0, { if (st1) { stage_unit(g1, d1, 0, 1); stage_unit(g1, d1, 0, 3); } }, )
    PHASE(1, 1, { if (st2) { stage_unit(g1 + 1, d, 0, 0); stage_unit(g1 + 1, d, 0, 2); } },
          asm volatile("s_waitcnt vmcnt(4)" ::: "memory");)
  }

  // epilogue: atomic accumulate (D: col = lane&15, row = (lane>>4)*4 + r)
  const int row0 = k * MBS + mt * 256 + wr * 128;
  const int col0 = ut * 256 + wc * 64;
#pragma unroll
  for (int nf = 0; nf < 4; ++nf) {
    const int col = col0 + nf * 16 + r15;
#pragma unroll
    for (int mf = 0; mf < 8; ++mf) {
      const int r0 = row0 + mf * 16 + hi * 4;
#pragma unroll
      for (int r = 0; r < 4; ++r)
        unsafeAtomicAdd(&out[(size_t)(r0 + r) * UQ + col], acc[mf][nf][r]);
    }
  }
}

// Fallback (ws too small): correct fp32 path, slow.
__global__ void ga_naive(const float* __restrict__ x, const float* __restrict__ w,
                         const float* __restrict__ bias, float* __restrict__ out) {
  int col = blockIdx.x * 256 + threadIdx.x;
  int row = blockIdx.y;
  int k = row >> 9, m = row & 511;
  float acc = bias[k * UQ + col];
  for (int i = 0; i < 8; ++i) {
    int j = c_sigma[i][k];
    float s = (float)c_sg[i][k];
    const float* xr = x + (size_t)(i * MBS + m) * CIN;
    const float* wc = w + (size_t)j * UQ + col;
    float a = 0.f;
    for (int c = 0; c < CIN; ++c) a = fmaf(xr[c], wc[(size_t)c * (NBL * UQ)], a);
    acc = fmaf(s, a, acc);
  }
  out[(size_t)row * UQ + col] = acc;
}

extern "C" void kernel_launch(void* const* d_in, const int* in_sizes, int n_in,
                              void* d_out, int out_size, void* d_ws, size_t ws_size,
                              hipStream_t stream) {
  const float* x    = (const float*)d_in[0];   // 4096*1024
  const float* W    = (const float*)d_in[1];   // 1024*8192
  const float* bias = (const float*)d_in[2];   // 8192
  float* out = (float*)d_out;                  // 4096*1024

  const size_t need = 32u * 1024u * 1024u;     // X+ 8MB, X- 8MB, Wt 16MB
  if (ws_size < need) {
    ga_naive<<<dim3(4, 4096), dim3(256), 0, stream>>>(x, W, bias, out);
    return;
  }

  uint16_t* xp = (uint16_t*)d_ws;
  uint16_t* xn = xp + 4194304;
  uint16_t* wt = xn + 4194304;

  cvt_x_kernel<<<dim3(2048), dim3(256), 0, stream>>>(
      (const float4*)x, (uint4*)xp, (uint4*)xn);
  cvt_w_kernel<<<dim3(256, 32), dim3(256), 0, stream>>>(W, wt);
  bias_fill<<<dim3(4096), dim3(256), 0, stream>>>(bias, (float4*)out);
  ga_gemm8<<<dim3(256), dim3(512), 131072, stream>>>(xp, xn, wt, out);
}

// Round 5
// 129.298 us; speedup vs baseline: 1.0418x; 1.0418x over previous
//
#include <hip/hip_runtime.h>
#include <stdint.h>

#define NBL 8
#define MBS 512   // rows per blade
#define CIN 1024  // K per blade block
#define UQ  1024  // output cols per blade

// sigma[i][k]: j such that blade_i * blade_j = sign * blade_k ; sg[i][k] = sign
__device__ __constant__ int c_sigma[8][8] = {
  {0,1,2,3,4,5,6,7},
  {1,0,4,5,2,3,7,6},
  {2,4,0,6,1,7,3,5},
  {3,5,6,0,7,1,2,4},
  {4,2,1,7,0,6,5,3},
  {5,3,7,1,6,0,4,2},
  {6,7,3,2,5,4,0,1},
  {7,6,5,4,3,2,1,0},
};
__device__ __constant__ int c_sg[8][8] = {
  { 1, 1, 1, 1, 1, 1, 1, 1},
  { 1, 1, 1, 1, 1, 1, 1, 1},
  { 1,-1, 1, 1,-1,-1, 1,-1},
  { 1,-1,-1, 1, 1,-1,-1, 1},
  {-1, 1,-1,-1, 1, 1,-1, 1},
  {-1, 1, 1,-1,-1, 1, 1,-1},
  {-1,-1, 1,-1, 1,-1, 1, 1},
  {-1,-1, 1,-1, 1,-1, 1, 1},
};

typedef short bf16x8 __attribute__((ext_vector_type(8)));
typedef float f32x4 __attribute__((ext_vector_type(4)));

__device__ __forceinline__ uint32_t f2bf(float f) {
  uint32_t u = __float_as_uint(f);
  return (u + 0x7fffu + ((u >> 16) & 1u)) >> 16;  // RNE
}
__device__ __forceinline__ uint32_t pk2(float lo, float hi) {
  return f2bf(lo) | (f2bf(hi) << 16);
}

// x (4096x1024 f32) -> X+ bf16 and X- bf16 (sign flip = xor 0x8000)
__global__ void cvt_x_kernel(const float4* __restrict__ x,
                             uint4* __restrict__ xp, uint4* __restrict__ xn) {
  int idx = blockIdx.x * blockDim.x + threadIdx.x;
  float4 a = x[2 * idx];
  float4 b = x[2 * idx + 1];
  uint4 p;
  p.x = pk2(a.x, a.y); p.y = pk2(a.z, a.w);
  p.z = pk2(b.x, b.y); p.w = pk2(b.z, b.w);
  uint4 n;
  n.x = p.x ^ 0x80008000u; n.y = p.y ^ 0x80008000u;
  n.z = p.z ^ 0x80008000u; n.w = p.w ^ 0x80008000u;
  xp[idx] = p;
  xn[idx] = n;
}

// W [1024][8192] f32 -> Wt [8192][1024] bf16
__global__ void cvt_w_kernel(const float* __restrict__ w, uint16_t* __restrict__ wt) {
  __shared__ float tile[32][33];
  int tx = threadIdx.x & 31, ty = threadIdx.x >> 5;  // 32x8
  int n0 = blockIdx.x * 32;
  int c0 = blockIdx.y * 32;
#pragma unroll
  for (int r = 0; r < 4; ++r) {
    int c = c0 + ty + r * 8;
    tile[ty + r * 8][tx] = w[(size_t)c * 8192 + n0 + tx];
  }
  __syncthreads();
#pragma unroll
  for (int r = 0; r < 4; ++r) {
    int n = n0 + ty + r * 8;
    wt[(size_t)n * 1024 + c0 + tx] = (uint16_t)f2bf(tile[tx][ty + r * 8]);
  }
}

// out[r][c] = bias[(r>>9)*1024 + c]  (prefill; GEMM atomically accumulates)
__global__ void bias_fill(const float* __restrict__ bias, float4* __restrict__ out) {
  int idx = blockIdx.x * 256 + threadIdx.x;
  int row = idx >> 8;
  int c4 = idx & 255;
  int k = row >> 9;
  out[idx] = ((const float4*)(bias + k * UQ))[c4];
}

// ---- 256x256x(BK=64) gray-code 4-phase GEMM, split-K=4 ----
// Per tile tau, phases compute quadrants (0,0),(0,1),(1,1),(1,0).
// Each fragment set read from LDS ONCE per tile (reads {4,8,8,4} per phase),
// issued one phase ahead of use. Stage ledger (units = 64 rows x 64 k):
//   p0: B0,B1(t+1)  p1: B2,B3(t+1)  p2: A1,A3(t+1)  p3: A0,A2(t+2)
// vmcnt (before closing barrier): p0:4 (lands A1A3(t) for p1 read),
//   p1:4 (lands A0A2(t+1) for p2 read), p2:2 (lands all B(t+1) for
//   p3-post/next-p0 reads), p3: none.

#define READ_A(DST, BUF, HALF)                                                \
  _Pragma("unroll")                                                           \
  for (int f = 0; f < 4; ++f) {                                               \
    const int R = wr * 128 + HALF * 64 + f * 16 + r15;                        \
    _Pragma("unroll")                                                         \
    for (int kk = 0; kk < 2; ++kk) {                                          \
      const int gc = kk * 4 + hi;                                             \
      DST[f][kk] = *(const bf16x8*)(dynlds + (size_t)((BUF)*2 + 0) * 16384 +  \
                                    R * 64 + ((gc ^ (R & 7)) << 3));          \
    }                                                                         \
  }

#define READ_B(DST, BUF, NH)                                                  \
  _Pragma("unroll")                                                           \
  for (int gg = 0; gg < 2; ++gg) {                                            \
    const int C = wc * 64 + NH * 32 + gg * 16 + r15;                          \
    _Pragma("unroll")                                                         \
    for (int kk = 0; kk < 2; ++kk) {                                          \
      const int gc = kk * 4 + hi;                                             \
      DST[gg][kk] = *(const bf16x8*)(dynlds + (size_t)((BUF)*2 + 1) * 16384 + \
                                     C * 64 + ((gc ^ (C & 7)) << 3));         \
    }                                                                         \
  }

#define MFMA16(AF, BF, MH, NH)                                                \
  __builtin_amdgcn_s_setprio(1);                                              \
  _Pragma("unroll")                                                           \
  for (int kk = 0; kk < 2; ++kk)                                              \
    _Pragma("unroll")                                                         \
    for (int f = 0; f < 4; ++f)                                               \
      _Pragma("unroll")                                                       \
      for (int gg = 0; gg < 2; ++gg)                                          \
        acc[MH * 4 + f][NH * 2 + gg] =                                        \
            __builtin_amdgcn_mfma_f32_16x16x32_bf16(                          \
                AF[f][kk], BF[gg][kk], acc[MH * 4 + f][NH * 2 + gg], 0, 0, 0);\
  __builtin_amdgcn_s_setprio(0);

#define BAR() do { asm volatile("s_barrier" ::: "memory");                    \
                   __builtin_amdgcn_sched_barrier(0); } while (0)
#define VMW(N) asm volatile("s_waitcnt vmcnt(" #N ")" ::: "memory")

__global__ __launch_bounds__(512, 1) void ga_gemm8(
    const uint16_t* __restrict__ xp, const uint16_t* __restrict__ xn,
    const uint16_t* __restrict__ wt, float* __restrict__ out) {
  extern __shared__ uint16_t dynlds[];  // [2 dbuf][A,B][256][64] = 128 KiB

  const int tid = threadIdx.x;
  const int bid = blockIdx.x;
  const int s   = bid >> 6;          // K-split 0..3
  const int rem = bid & 63;
  const int k   = rem >> 3;          // blade 0..7
  const int mt  = (rem >> 2) & 1;    // m-tile 0..1
  const int ut  = rem & 3;           // n-tile 0..3
  const int lane = tid & 63;
  const int wid  = tid >> 6;         // 0..7
  const int wr   = wid >> 2;         // 0..1
  const int wc   = wid & 3;          // 0..3
  const int r15 = lane & 15, hi = lane >> 4;

  f32x4 acc[8][4];
  const f32x4 z = {0.f, 0.f, 0.f, 0.f};
#pragma unroll
  for (int a = 0; a < 8; ++a)
#pragma unroll
    for (int b = 0; b < 4; ++b) acc[a][b] = z;

  // stage one 64-row unit (1 load/thread). part: 0=A,1=B. u: 0..3.
  auto stage_unit = [&](int g, int d_, int part, int u) {
    const int i  = g >> 4;
    const int c0 = (g & 15) << 6;
    const int rl = tid >> 3;                      // 0..63
    const int cs = (tid & 7) ^ (rl & 7);          // T2 pre-swizzled source chunk
    const uint16_t* src;
    if (part == 0) {
      src = ((c_sg[i][k] > 0) ? xp : xn) +
            (size_t)(i * MBS + mt * 256 + u * 64 + rl) * CIN + c0 + cs * 8;
    } else {
      src = wt + (size_t)(c_sigma[i][k] * UQ + ut * 256 + u * 64 + rl) * CIN + c0 + cs * 8;
    }
    uint16_t* dst = dynlds + (size_t)(d_ * 2 + part) * 16384 + (u * 512 + tid) * 8;
    __builtin_amdgcn_global_load_lds(
        (const __attribute__((address_space(1))) uint32_t*)src,
        (__attribute__((address_space(3))) uint32_t*)dst, 16, 0, 0);
  };

  const int t0 = s * 32;  // 32 K-tiles of 64 per block

  // prologue: issue order matches steady-state ledger expectations
  stage_unit(t0, 0, 0, 0); stage_unit(t0, 0, 0, 2);          // A0,A2(t0)
  stage_unit(t0, 0, 1, 0); stage_unit(t0, 0, 1, 1);          // B0,B1(t0)
  stage_unit(t0, 0, 1, 2); stage_unit(t0, 0, 1, 3);          // B2,B3(t0)
  stage_unit(t0, 0, 0, 1); stage_unit(t0, 0, 0, 3);          // A1,A3(t0)
  stage_unit(t0 + 1, 1, 0, 0); stage_unit(t0 + 1, 1, 0, 2);  // A0,A2(t0+1)
  VMW(4);  // lands A0A2(t0)+B(t0); A1A3(t0),A0A2(t0+1) stay outstanding
  BAR();

  bf16x8 afE[4][2], afO[4][2], bf0[2][2], bf1[2][2];
  READ_A(afE, 0, 0);   // A0(t0)
  READ_B(bf0, 0, 0);   // B0(t0)

  for (int tau = 0; tau < 32; ++tau) {
    const int d  = tau & 1;
    const int d1 = d ^ 1;
    const int g1 = t0 + tau + 1;
    const bool st1 = tau < 31;
    const bool st2 = tau < 30;
    // ---- p0: compute (0,0); read B1(tau); stage B0,B1(tau+1)
    READ_B(bf1, d, 1);
    if (st1) { stage_unit(g1, d1, 1, 0); stage_unit(g1, d1, 1, 1); }
    BAR();
    MFMA16(afE, bf0, 0, 0);
    VMW(4);
    BAR();
    // ---- p1: compute (0,1); read A1(tau); stage B2,B3(tau+1)
    READ_A(afO, d, 1);
    if (st1) { stage_unit(g1, d1, 1, 2); stage_unit(g1, d1, 1, 3); }
    BAR();
    MFMA16(afE, bf1, 0, 1);
    VMW(4);
    BAR();
    // ---- p2: compute (1,1); read A0(tau+1); stage A1,A3(tau+1)
    if (st1) { READ_A(afE, d1, 0); }
    if (st1) { stage_unit(g1, d1, 0, 1); stage_unit(g1, d1, 0, 3); }
    BAR();
    MFMA16(afO, bf1, 1, 1);
    VMW(2);
    BAR();
    // ---- p3: compute (1,0); stage A0,A2(tau+2); read B0(tau+1) after MFMA
    if (st2) { stage_unit(g1 + 1, d, 0, 0); stage_unit(g1 + 1, d, 0, 2); }
    BAR();
    MFMA16(afO, bf0, 1, 0);
    if (st1) { READ_B(bf0, d1, 0); }
    BAR();
  }

  // epilogue: atomic accumulate (D: col = lane&15, row = (lane>>4)*4 + r)
  const int row0 = k * MBS + mt * 256 + wr * 128;
  const int col0 = ut * 256 + wc * 64;
#pragma unroll
  for (int nf = 0; nf < 4; ++nf) {
    const int col = col0 + nf * 16 + r15;
#pragma unroll
    for (int mf = 0; mf < 8; ++mf) {
      const int r0 = row0 + mf * 16 + hi * 4;
#pragma unroll
      for (int r = 0; r < 4; ++r)
        unsafeAtomicAdd(&out[(size_t)(r0 + r) * UQ + col], acc[mf][nf][r]);
    }
  }
}

// Fallback (ws too small): correct fp32 path, slow.
__global__ void ga_naive(const float* __restrict__ x, const float* __restrict__ w,
                         const float* __restrict__ bias, float* __restrict__ out) {
  int col = blockIdx.x * 256 + threadIdx.x;
  int row = blockIdx.y;
  int k = row >> 9, m = row & 511;
  float acc = bias[k * UQ + col];
  for (int i = 0; i < 8; ++i) {
    int j = c_sigma[i][k];
    float s = (float)c_sg[i][k];
    const float* xr = x + (size_t)(i * MBS + m) * CIN;
    const float* wc = w + (size_t)j * UQ + col;
    float a = 0.f;
    for (int c = 0; c < CIN; ++c) a = fmaf(xr[c], wc[(size_t)c * (NBL * UQ)], a);
    acc = fmaf(s, a, acc);
  }
  out[(size_t)row * UQ + col] = acc;
}

extern "C" void kernel_launch(void* const* d_in, const int* in_sizes, int n_in,
                              void* d_out, int out_size, void* d_ws, size_t ws_size,
                              hipStream_t stream) {
  const float* x    = (const float*)d_in[0];   // 4096*1024
  const float* W    = (const float*)d_in[1];   // 1024*8192
  const float* bias = (const float*)d_in[2];   // 8192
  float* out = (float*)d_out;                  // 4096*1024

  const size_t need = 32u * 1024u * 1024u;     // X+ 8MB, X- 8MB, Wt 16MB
  if (ws_size < need) {
    ga_naive<<<dim3(4, 4096), dim3(256), 0, stream>>>(x, W, bias, out);
    return;
  }

  uint16_t* xp = (uint16_t*)d_ws;
  uint16_t* xn = xp + 4194304;
  uint16_t* wt = xn + 4194304;

  cvt_x_kernel<<<dim3(2048), dim3(256), 0, stream>>>(
      (const float4*)x, (uint4*)xp, (uint4*)xn);
  cvt_w_kernel<<<dim3(256, 32), dim3(256), 0, stream>>>(W, wt);
  bias_fill<<<dim3(4096), dim3(256), 0, stream>>>(bias, (float4*)out);
  ga_gemm8<<<dim3(256), dim3(512), 131072, stream>>>(xp, xn, wt, out);
}

// Round 6
// 105.037 us; speedup vs baseline: 1.2824x; 1.2310x over previous
//
#include <hip/hip_runtime.h>
#include <stdint.h>

#define NBL 8
#define MBS 512   // rows per blade
#define CIN 1024  // K per blade block
#define UQ  1024  // output cols per blade

// sigma[i][k]: j such that blade_i * blade_j = sign * blade_k ; sg[i][k] = sign
__device__ __constant__ int c_sigma[8][8] = {
  {0,1,2,3,4,5,6,7},
  {1,0,4,5,2,3,7,6},
  {2,4,0,6,1,7,3,5},
  {3,5,6,0,7,1,2,4},
  {4,2,1,7,0,6,5,3},
  {5,3,7,1,6,0,4,2},
  {6,7,3,2,5,4,0,1},
  {7,6,5,4,3,2,1,0},
};
__device__ __constant__ int c_sg[8][8] = {
  { 1, 1, 1, 1, 1, 1, 1, 1},
  { 1, 1, 1, 1, 1, 1, 1, 1},
  { 1,-1, 1, 1,-1,-1, 1,-1},
  { 1,-1,-1, 1, 1,-1,-1, 1},
  {-1, 1,-1,-1, 1, 1,-1, 1},
  {-1, 1, 1,-1,-1, 1, 1,-1},
  {-1,-1, 1,-1, 1,-1, 1, 1},
  {-1,-1, 1,-1, 1,-1, 1, 1},
};

typedef short bf16x8 __attribute__((ext_vector_type(8)));
typedef float f32x4 __attribute__((ext_vector_type(4)));

__device__ __forceinline__ uint32_t f2bf(float f) {
  uint32_t u = __float_as_uint(f);
  return (u + 0x7fffu + ((u >> 16) & 1u)) >> 16;  // RNE
}
__device__ __forceinline__ uint32_t pk2(float lo, float hi) {
  return f2bf(lo) | (f2bf(hi) << 16);
}

// ---------------- prepass: blocked workspace layouts ----------------
// X'[i][chunk c 0..127][row m 0..511][8 elems]  (+ and - sign copies)
// W'[j][chunk c 0..127][col u 0..1023][8 elems]
// where chunk c covers k = c*8..c*8+7 within the blade's K=1024.

// x (4096x1024 f32) -> Xp'/Xn' blocked bf16. Block: 32 chunks x 32 rows.
__global__ void cvt_x_kernel(const float* __restrict__ x,
                             uint4* __restrict__ xp, uint4* __restrict__ xn) {
  __shared__ uint4 t16[32 * 33];  // [chunk 32][row 32], stride 33 (pad)
  const int tid = threadIdx.x;           // 256
  const int tx = tid & 31, ty = tid >> 5;
  const int i  = blockIdx.x >> 2;        // blade 0..7
  const int cb = blockIdx.x & 3;         // chunk-block 0..3 (32 chunks each)
  const int m0 = blockIdx.y * 32;        // row-block
#pragma unroll
  for (int r = 0; r < 4; ++r) {
    const int m = m0 + ty + r * 8;
    const float* src = x + ((size_t)(i * MBS + m)) * CIN + cb * 256 + tx * 8;
    float4 a = *(const float4*)src;
    float4 b = *(const float4*)(src + 4);
    uint4 p;
    p.x = pk2(a.x, a.y); p.y = pk2(a.z, a.w);
    p.z = pk2(b.x, b.y); p.w = pk2(b.z, b.w);
    t16[tx * 33 + ty + r * 8] = p;  // [chunk tx][row]
  }
  __syncthreads();
#pragma unroll
  for (int p = 0; p < 4; ++p) {
    const int slot = p * 256 + tid;      // 1024 slots
    const int cc = slot >> 5, mm = slot & 31;
    uint4 v = t16[cc * 33 + mm];
    const size_t o = (size_t)(i * 128 + cb * 32 + cc) * 512 + m0 + mm;
    xp[o] = v;
    uint4 n;
    n.x = v.x ^ 0x80008000u; n.y = v.y ^ 0x80008000u;
    n.z = v.z ^ 0x80008000u; n.w = v.w ^ 0x80008000u;
    xn[o] = n;
  }
}

// W [1024][8192] f32 -> W' blocked bf16 (transpose k<->u).
__global__ void cvt_w_kernel(const float* __restrict__ w, uint4* __restrict__ wp) {
  __shared__ float tile[32][33];
  const int tid = threadIdx.x;  // 256
  const int tx = tid & 31, ty = tid >> 5;
  const int n0 = blockIdx.x * 32;   // over 8192 n
  const int k0 = blockIdx.y * 32;   // over 1024 k
#pragma unroll
  for (int r = 0; r < 4; ++r) {
    const int kk = k0 + ty + r * 8;
    tile[ty + r * 8][tx] = w[(size_t)kk * 8192 + n0 + tx];
  }
  __syncthreads();
  if (tid < 128) {
    const int cc = tid >> 5;   // 0..3 local chunk
    const int uu = tid & 31;
    const int j = n0 >> 10;
    const int ucol = (n0 & 1023) + uu;
    uint4 v;
    v.x = pk2(tile[cc * 8 + 0][uu], tile[cc * 8 + 1][uu]);
    v.y = pk2(tile[cc * 8 + 2][uu], tile[cc * 8 + 3][uu]);
    v.z = pk2(tile[cc * 8 + 4][uu], tile[cc * 8 + 5][uu]);
    v.w = pk2(tile[cc * 8 + 6][uu], tile[cc * 8 + 7][uu]);
    wp[(size_t)(j * 128 + blockIdx.y * 4 + cc) * 1024 + ucol] = v;
  }
}

// out[r][c] = bias[(r>>9)*1024 + c]  (prefill; GEMM atomically accumulates)
__global__ void bias_fill(const float* __restrict__ bias, float4* __restrict__ out) {
  int idx = blockIdx.x * 256 + threadIdx.x;
  int row = idx >> 8;
  int c4 = idx & 255;
  int k = row >> 9;
  out[idx] = ((const float4*)(bias + k * UQ))[c4];
}

#define BAR() do { asm volatile("s_barrier" ::: "memory");                    \
                   __builtin_amdgcn_sched_barrier(0); } while (0)
#define VMW(N) asm volatile("s_waitcnt vmcnt(" #N ")" ::: "memory")

// ---- 128x128x(BK=32) ring-4 GEMM, split-K=2, prefetch depth 3 ----
// 2 blocks/CU (64 KB LDS, <=168 VGPR). One vmcnt(8)+barrier per step;
// stage(t) forced landed at end of step t-1 (issued at t-3: ~3 steps slack).
// LDS tile layout: [chunk 0..3][row 0..127][8 elems] -> b128 reads hit the
// 8-touch/bank minimum without any XOR (same class as round-3's measured 0).
__global__ __launch_bounds__(256, 2) void ga_ring(
    const uint16_t* __restrict__ xp, const uint16_t* __restrict__ xn,
    const uint16_t* __restrict__ wp, float* __restrict__ out) {
  __shared__ uint16_t lds[4][8192];  // ring: [buf][A 4096 | B 4096] = 64 KB

  const int tid  = threadIdx.x;
  const int bid  = blockIdx.x;
  const int s    = bid >> 8;          // K-split 0/1 (4 i-blocks each)
  const int k    = (bid >> 5) & 7;
  const int mt   = (bid >> 3) & 3;
  const int ut   = bid & 7;
  const int lane = tid & 63;
  const int wid  = tid >> 6;
  const int wr   = wid >> 1, wc = wid & 1;  // 2x2 waves, each 64x64 out
  const int r15  = lane & 15, hi = lane >> 4;

  // hoisted uniform tables: j and sign for the 4 i-blocks this split covers
  uint32_t sig_pack = 0, pos_pack = 0;
#pragma unroll
  for (int ib = 0; ib < 4; ++ib) {
    sig_pack |= (uint32_t)c_sigma[s * 4 + ib][k] << (4 * ib);
    pos_pack |= (uint32_t)(c_sg[s * 4 + ib][k] > 0) << ib;
  }
  const int hc = tid >> 7;                     // 0/1 within a stage call
  const size_t mrow8 = (size_t)(mt * 128 + (tid & 127)) * 8;
  const size_t urow8 = (size_t)(ut * 128 + (tid & 127)) * 8;

  f32x4 acc[4][4];
  const f32x4 z = {0.f, 0.f, 0.f, 0.f};
#pragma unroll
  for (int a = 0; a < 4; ++a)
#pragma unroll
    for (int b = 0; b < 4; ++b) acc[a][b] = z;

  // stage step u (BK=32 = 4 chunks): 2 A-loads + 2 B-loads per thread-call
  auto stage = [&](int u) {
    const int ib = u >> 5;
    const int c0 = (u & 31) << 2;               // chunk base within i-block
    const int j  = (sig_pack >> (4 * ib)) & 15;
    const uint16_t* xb = ((pos_pack >> ib) & 1) ? xp : xn;
    const size_t abase = ((size_t)(s * 4 + ib) << 19);        // i*128*512*8
    const size_t bbase = ((size_t)j << 20);                   // j*128*1024*8
    uint16_t* la = lds[u & 3];
    uint16_t* lb = lds[u & 3] + 4096;
#pragma unroll
    for (int u2 = 0; u2 < 2; ++u2) {
      const int cc = c0 + u2 * 2 + hc;
      __builtin_amdgcn_global_load_lds(
          (const __attribute__((address_space(1))) uint32_t*)(xb + abase + (size_t)cc * 4096 + mrow8),
          (__attribute__((address_space(3))) uint32_t*)(la + (u2 * 256 + tid) * 8), 16, 0, 0);
      __builtin_amdgcn_global_load_lds(
          (const __attribute__((address_space(1))) uint32_t*)(wp + bbase + (size_t)cc * 8192 + urow8),
          (__attribute__((address_space(3))) uint32_t*)(lb + (u2 * 256 + tid) * 8), 16, 0, 0);
    }
  };

  stage(0); stage(1); stage(2);
  VMW(8);   // forces stage(0) landed; stage(1),(2) stay in flight
  BAR();

  for (int t = 0; t < 128; ++t) {
    const int nt = (t + 3 < 127) ? t + 3 : 127;  // clamped: tail dups are benign
    stage(nt);
    const uint16_t* base = lds[t & 3];
    bf16x8 af[4], bfr[4];
#pragma unroll
    for (int f = 0; f < 4; ++f)
      af[f] = *(const bf16x8*)(base + ((hi << 7) + wr * 64 + f * 16 + r15) * 8);
#pragma unroll
    for (int g = 0; g < 4; ++g)
      bfr[g] = *(const bf16x8*)(base + 4096 + ((hi << 7) + wc * 64 + g * 16 + r15) * 8);
    __builtin_amdgcn_s_setprio(1);
#pragma unroll
    for (int f = 0; f < 4; ++f)
#pragma unroll
      for (int g = 0; g < 4; ++g)
        acc[f][g] = __builtin_amdgcn_mfma_f32_16x16x32_bf16(
            af[f], bfr[g], acc[f][g], 0, 0, 0);
    __builtin_amdgcn_s_setprio(0);
    VMW(8);   // forces stage(t+1) landed by end of this step (issued at t-2)
    BAR();
  }

  // epilogue: atomic accumulate (D: col = lane&15, row = (lane>>4)*4 + r)
  const int row0 = k * MBS + mt * 128 + wr * 64;
  const int col0 = ut * 128 + wc * 64;
#pragma unroll
  for (int g = 0; g < 4; ++g) {
    const int col = col0 + g * 16 + r15;
#pragma unroll
    for (int f = 0; f < 4; ++f) {
      const int r0 = row0 + f * 16 + hi * 4;
#pragma unroll
      for (int r = 0; r < 4; ++r)
        unsafeAtomicAdd(&out[(size_t)(r0 + r) * UQ + col], acc[f][g][r]);
    }
  }
}

// Fallback (ws too small): correct fp32 path, slow.
__global__ void ga_naive(const float* __restrict__ x, const float* __restrict__ w,
                         const float* __restrict__ bias, float* __restrict__ out) {
  int col = blockIdx.x * 256 + threadIdx.x;
  int row = blockIdx.y;
  int k = row >> 9, m = row & 511;
  float acc = bias[k * UQ + col];
  for (int i = 0; i < 8; ++i) {
    int j = c_sigma[i][k];
    float s = (float)c_sg[i][k];
    const float* xr = x + (size_t)(i * MBS + m) * CIN;
    const float* wc = w + (size_t)j * UQ + col;
    float a = 0.f;
    for (int c = 0; c < CIN; ++c) a = fmaf(xr[c], wc[(size_t)c * (NBL * UQ)], a);
    acc = fmaf(s, a, acc);
  }
  out[(size_t)row * UQ + col] = acc;
}

extern "C" void kernel_launch(void* const* d_in, const int* in_sizes, int n_in,
                              void* d_out, int out_size, void* d_ws, size_t ws_size,
                              hipStream_t stream) {
  const float* x    = (const float*)d_in[0];   // 4096*1024
  const float* W    = (const float*)d_in[1];   // 1024*8192
  const float* bias = (const float*)d_in[2];   // 8192
  float* out = (float*)d_out;                  // 4096*1024

  const size_t need = 32u * 1024u * 1024u;     // Xp' 8MB, Xn' 8MB, W' 16MB
  if (ws_size < need) {
    ga_naive<<<dim3(4, 4096), dim3(256), 0, stream>>>(x, W, bias, out);
    return;
  }

  uint16_t* xp = (uint16_t*)d_ws;
  uint16_t* xn = xp + 4194304;
  uint16_t* wp = xn + 4194304;

  cvt_x_kernel<<<dim3(32, 16), dim3(256), 0, stream>>>(x, (uint4*)xp, (uint4*)xn);
  cvt_w_kernel<<<dim3(256, 32), dim3(256), 0, stream>>>(W, (uint4*)wp);
  bias_fill<<<dim3(4096), dim3(256), 0, stream>>>(bias, (float4*)out);
  ga_ring<<<dim3(512), dim3(256), 0, stream>>>(xp, xn, wp, out);
}